// Round 3
// baseline (1875.656 us; speedup 1.0000x reference)
//
#include <hip/hip_runtime.h>

#define B_ 8
#define S_ 4096
#define H_ 768
#define C_ 64
#define NB_ 64
#define M_ (B_*S_)   // 32768 rows

typedef _Float16 f16x8 __attribute__((ext_vector_type(8)));
typedef _Float16 f16x4 __attribute__((ext_vector_type(4)));
typedef float    f32x4 __attribute__((ext_vector_type(4)));

// ---------------------------------------------------------------------------
// Weight transpose + f16 cast: WT[n][k] = (f16) W[k][n]
// ---------------------------------------------------------------------------
__global__ __launch_bounds__(256) void k_transpose(const float* __restrict__ src,
                                                   _Float16* __restrict__ dst) {
  __shared__ float tile[32][33];
  const int t = threadIdx.x;
  const int tx = t & 31, ty = t >> 5;
  const int n0 = blockIdx.x * 32, k0 = blockIdx.y * 32;
#pragma unroll
  for (int i = 0; i < 4; ++i)
    tile[ty + i*8][tx] = src[(k0 + ty + i*8) * H_ + n0 + tx];
  __syncthreads();
#pragma unroll
  for (int i = 0; i < 4; ++i)
    dst[(n0 + ty + i*8) * H_ + k0 + tx] = (_Float16)tile[tx][ty + i*8];
}

// ---------------------------------------------------------------------------
// Fused Q/K/V GEMM (f16 MFMA 16x16x32). Tile 64(M) x 128(N), 256 threads.
// Outputs: Qb[s][h] row-major; KT[b][h][s], VT[b][d][s] transposed.
// ---------------------------------------------------------------------------
__global__ __launch_bounds__(256) void k_gemm_qkv(
    const float* __restrict__ x,
    const _Float16* __restrict__ WqT, const _Float16* __restrict__ WkT,
    const _Float16* __restrict__ WvT,
    _Float16* __restrict__ Qb, _Float16* __restrict__ KT, _Float16* __restrict__ VT) {
  __shared__ _Float16 xs[64][40];
  __shared__ _Float16 ws[3][128][40];
  const int t = threadIdx.x;
  const int m0 = blockIdx.x * 64, n0 = blockIdx.y * 128;
  const int lane = t & 63, wv = t >> 6;
  const int lm = lane & 15, qd = lane >> 4;
  const int sm = t >> 2, sk = (t & 3) * 8;
  const int wn = t >> 1, wk = (t & 1) * 16;

  f32x4 acc[3][4][2];
#pragma unroll
  for (int a = 0; a < 3; ++a)
#pragma unroll
    for (int i = 0; i < 4; ++i)
#pragma unroll
      for (int n = 0; n < 2; ++n)
        acc[a][i][n] = (f32x4){0.f, 0.f, 0.f, 0.f};

  for (int kk = 0; kk < 24; ++kk) {
    const int k0 = kk * 32;
    __syncthreads();
    {
      const f32x4* xp = (const f32x4*)&x[(size_t)(m0 + sm) * H_ + k0 + sk];
      f32x4 f0 = xp[0], f1 = xp[1];
      f16x8 xv;
#pragma unroll
      for (int j = 0; j < 4; ++j) { xv[j] = (_Float16)f0[j]; xv[4 + j] = (_Float16)f1[j]; }
      *(f16x8*)&xs[sm][sk] = xv;
    }
    {
      const f16x8* wp = (const f16x8*)&WqT[(n0 + wn) * H_ + k0 + wk];
      *(f16x8*)&ws[0][wn][wk] = wp[0]; *(f16x8*)&ws[0][wn][wk + 8] = wp[1];
      wp = (const f16x8*)&WkT[(n0 + wn) * H_ + k0 + wk];
      *(f16x8*)&ws[1][wn][wk] = wp[0]; *(f16x8*)&ws[1][wn][wk + 8] = wp[1];
      wp = (const f16x8*)&WvT[(n0 + wn) * H_ + k0 + wk];
      *(f16x8*)&ws[2][wn][wk] = wp[0]; *(f16x8*)&ws[2][wn][wk + 8] = wp[1];
    }
    __syncthreads();
    f16x8 af[4];
#pragma unroll
    for (int i = 0; i < 4; ++i) af[i] = *(f16x8*)&xs[i*16 + lm][qd*8];
#pragma unroll
    for (int a = 0; a < 3; ++a)
#pragma unroll
      for (int n = 0; n < 2; ++n) {
        f16x8 bfr = *(f16x8*)&ws[a][wv*32 + n*16 + lm][qd*8];
#pragma unroll
        for (int i = 0; i < 4; ++i)
          acc[a][i][n] = __builtin_amdgcn_mfma_f32_16x16x32_f16(af[i], bfr, acc[a][i][n], 0, 0, 0);
      }
  }
#pragma unroll
  for (int i = 0; i < 4; ++i)
#pragma unroll
    for (int n = 0; n < 2; ++n) {
      const int ng = n0 + wv*32 + n*16 + lm;
      const int mg0 = m0 + i*16 + qd*4;
      const int bb = mg0 >> 12, ss = mg0 & (S_ - 1);
#pragma unroll
      for (int r = 0; r < 4; ++r)
        Qb[(size_t)(mg0 + r) * H_ + ng] = (_Float16)acc[0][i][n][r];
      f16x4 kp, vp;
#pragma unroll
      for (int r = 0; r < 4; ++r) {
        kp[r] = (_Float16)acc[1][i][n][r];
        vp[r] = (_Float16)acc[2][i][n][r];
      }
      *(f16x4*)&KT[((size_t)bb * H_ + ng) * S_ + ss] = kp;
      *(f16x4*)&VT[((size_t)bb * H_ + ng) * S_ + ss] = vp;
    }
}

// ---------------------------------------------------------------------------
// t = x @ W1   [32768 x 16]
// ---------------------------------------------------------------------------
__global__ __launch_bounds__(256) void k_tgemm(const float* __restrict__ x,
                                               const float* __restrict__ W1,
                                               float* __restrict__ tbuf) {
  __shared__ float w1s[768 * 16];
  __shared__ float xs[64 * 129];
  const int t = threadIdx.x;
  const int m0 = blockIdx.x * 64;
  for (int i = t; i < 768 * 16 / 4; i += 256)
    ((f32x4*)w1s)[i] = ((const f32x4*)W1)[i];
  const int row = t & 63, cg = t >> 6;
  f32x4 acc = (f32x4){0.f, 0.f, 0.f, 0.f};
  for (int kc = 0; kc < 768; kc += 128) {
    __syncthreads();
    for (int i = 0; i < 32; ++i) {
      const int idx = t + 256 * i;
      const int r = idx >> 7, c = idx & 127;
      xs[r * 129 + c] = x[(size_t)(m0 + r) * H_ + kc + c];
    }
    __syncthreads();
#pragma unroll 8
    for (int kl = 0; kl < 128; ++kl) {
      const float a = xs[row * 129 + kl];
      const f32x4 w = *(const f32x4*)&w1s[(kc + kl) * 16 + cg * 4];
#pragma unroll
      for (int j = 0; j < 4; ++j) acc[j] += a * w[j];
    }
  }
  *(f32x4*)&tbuf[(size_t)(m0 + row) * 16 + cg * 4] = acc;
}

// ---------------------------------------------------------------------------
// a[b,h] = mean_s sigmoid((t@W2)[b,s,h] + bias[h]) ^ (1/16)
// ---------------------------------------------------------------------------
__global__ __launch_bounds__(256) void k_areduce(const float* __restrict__ tbuf,
                                                 const float* __restrict__ W2,
                                                 const float* __restrict__ bias,
                                                 float* __restrict__ abuf) {
  __shared__ float ts[128 * 17];
  __shared__ float rbuf[8 * 32];
  const int t = threadIdx.x;
  const int b = blockIdx.y, hc = blockIdx.x;
  const int hl = t & 31, sg = t >> 5;
  const int h = hc * 32 + hl;
  float w2r[16];
#pragma unroll
  for (int j = 0; j < 16; ++j) w2r[j] = W2[j * H_ + h];
  const float bb = bias[h];
  float asum = 0.f;
  const float* tb = &tbuf[(size_t)(b * S_) * 16];
  for (int sc = 0; sc < S_; sc += 128) {
    __syncthreads();
    for (int i = 0; i < 8; ++i) {
      const int idx = t + 256 * i;
      const int sl = idx >> 4, j = idx & 15;
      ts[sl * 17 + j] = tb[(size_t)(sc + sl) * 16 + j];
    }
    __syncthreads();
    for (int i = 0; i < 16; ++i) {
      const int sl = sg + i * 8;
      float z = bb;
      const float* tr = &ts[sl * 17];
#pragma unroll
      for (int j = 0; j < 16; ++j) z += tr[j] * w2r[j];
      const float sgm = 1.f / (1.f + __expf(-z));
      asum += sqrtf(sqrtf(sqrtf(sqrtf(sgm))));
    }
  }
  rbuf[sg * 32 + hl] = asum;
  __syncthreads();
  if (t < 32) {
    float s = 0.f;
#pragma unroll
    for (int g = 0; g < 8; ++g) s += rbuf[g * 32 + t];
    abuf[b * H_ + hc * 32 + t] = s * (1.f / (float)S_);
  }
}

// ---------------------------------------------------------------------------
// MFMA scores+Y: S=Q.K^T (K LDS-transposed from KT), masked-softmax, O=w.V
// via O^T-orientation MFMA (A=VT, B=w). grid (64 nb, 8 b), 256 thr / 4 waves.
// Writes O fully (scan partials added later by k_reduce).
// ---------------------------------------------------------------------------
__global__ __launch_bounds__(256) void k_scores_y(
    const _Float16* __restrict__ Qb, const _Float16* __restrict__ KT,
    const _Float16* __restrict__ VT, float* __restrict__ O) {
  __shared__ _Float16 sbuf[64 * 136];   // phase1: Ks[d][h%128] (136 stride); later wb[c][d] (72 stride)
  const int t = threadIdx.x;
  const int nb = blockIdx.x, b = blockIdx.y;
  const int s0 = nb * 64;
  const int w = t >> 6, lane = t & 63;
  const int lm = lane & 15, qd = lane >> 4;

  f32x4 sc[4];
#pragma unroll
  for (int nt = 0; nt < 4; ++nt) sc[nt] = (f32x4){0.f, 0.f, 0.f, 0.f};

  // ---- phase 1: S[c][d] = sum_h Q[c][h] K[d][h] ----
  for (int hr = 0; hr < 6; ++hr) {
    __syncthreads();
    { // stage Ks[d 0..63][hl 0..127] from KT[h][s]
      const int hl = t >> 1, dseg = (t & 1) * 32;
      const size_t krow = ((size_t)b * H_ + hr * 128 + hl) * S_ + s0 + dseg;
#pragma unroll
      for (int j = 0; j < 4; ++j) {
        f16x8 kv = *(const f16x8*)&KT[krow + j * 8];
#pragma unroll
        for (int u = 0; u < 8; ++u) sbuf[(dseg + j * 8 + u) * 136 + hl] = kv[u];
      }
    }
    __syncthreads();
    const size_t qrow = ((size_t)b * S_ + s0 + w * 16 + lm) * H_ + hr * 128 + qd * 8;
#pragma unroll
    for (int ktl = 0; ktl < 4; ++ktl) {
      f16x8 qa = *(const f16x8*)&Qb[qrow + ktl * 32];
#pragma unroll
      for (int nt = 0; nt < 4; ++nt) {
        f16x8 kb = *(f16x8*)&sbuf[(nt * 16 + lm) * 136 + ktl * 32 + qd * 8];
        sc[nt] = __builtin_amdgcn_mfma_f32_16x16x32_f16(qa, kb, sc[nt], 0, 0, 0);
      }
    }
  }
  __syncthreads();   // Ks reads done; sbuf reused as wb
  // ---- phase 2: mask-by-mult, softmax (zeros included), write wb[c][d] f16 ----
  const float scale = 0.036084391824351615f;  // 1/sqrt(768)
#pragma unroll
  for (int r = 0; r < 4; ++r) {
    const int c = w * 16 + qd * 4 + r;
    float v[4]; float mx = -1e30f;
#pragma unroll
    for (int nt = 0; nt < 4; ++nt) {
      const int d = nt * 16 + lm;
      v[nt] = (d <= c) ? sc[nt][r] * scale : 0.f;
      mx = fmaxf(mx, v[nt]);
    }
    mx = fmaxf(mx, __shfl_xor(mx, 1));
    mx = fmaxf(mx, __shfl_xor(mx, 2));
    mx = fmaxf(mx, __shfl_xor(mx, 4));
    mx = fmaxf(mx, __shfl_xor(mx, 8));
    float sm = 0.f;
#pragma unroll
    for (int nt = 0; nt < 4; ++nt) { v[nt] = __expf(v[nt] - mx); sm += v[nt]; }
    sm += __shfl_xor(sm, 1);
    sm += __shfl_xor(sm, 2);
    sm += __shfl_xor(sm, 4);
    sm += __shfl_xor(sm, 8);
    const float inv = 1.f / sm;
#pragma unroll
    for (int nt = 0; nt < 4; ++nt)
      sbuf[c * 72 + nt * 16 + lm] = (_Float16)(v[nt] * inv);
  }
  __syncthreads();
  // ---- phase 3: O^T[e][c] = sum_d V^T[e][d] w^T[d][c]; A=VT, B=wb ----
  f16x8 wf[4][2];
#pragma unroll
  for (int nt = 0; nt < 4; ++nt)
#pragma unroll
    for (int kd = 0; kd < 2; ++kd)
      wf[nt][kd] = *(f16x8*)&sbuf[(nt * 16 + lm) * 72 + kd * 32 + qd * 8];
#pragma unroll 4
  for (int mt = 0; mt < 12; ++mt) {
    const int e0 = (w * 12 + mt) * 16;
    const size_t ar = ((size_t)b * H_ + e0 + lm) * S_ + s0 + qd * 8;
    f16x8 a0 = *(const f16x8*)&VT[ar];
    f16x8 a1 = *(const f16x8*)&VT[ar + 32];
#pragma unroll
    for (int nt = 0; nt < 4; ++nt) {
      f32x4 y = (f32x4){0.f, 0.f, 0.f, 0.f};
      y = __builtin_amdgcn_mfma_f32_16x16x32_f16(a0, wf[nt][0], y, 0, 0, 0);
      y = __builtin_amdgcn_mfma_f32_16x16x32_f16(a1, wf[nt][1], y, 0, 0, 0);
      *(f32x4*)&O[((size_t)b * S_ + s0 + nt * 16 + lm) * H_ + e0 + qd * 4] = y;
    }
  }
}

// ---------------------------------------------------------------------------
// MFMA scan, h-split into HC chunks. grid (24 d-tiles, HC, 8 b), 4 waves.
// Wave w owns MT=H/(HC*64) h-tiles of St (in acc regs). Per step:
//   St = St*a + K^T.V (MFMA, K/V frags double-buffered, prefetched post-barrier)
//   St -> LDS f16 (StL[d][h]); partial^T[d][s] = St^T.Q (A=StL, B=Q) -> P (f16)
// ---------------------------------------------------------------------------
template<int HC>
__global__ __launch_bounds__(256, (HC == 4 ? 3 : 2)) void k_scan(
    const _Float16* __restrict__ Qb, const _Float16* __restrict__ KT,
    const _Float16* __restrict__ VT, const float* __restrict__ abuf,
    _Float16* __restrict__ P, size_t pstride) {
  constexpr int HCH = H_ / HC;     // h per chunk: 192 (HC4) / 384 (HC2)
  constexpr int MT  = HCH / 64;    // m-tiles per wave: 3 / 6
  constexpr int KT2 = HCH / 32;    // output kt steps: 6 / 12
  constexpr int STP = HCH + 8;     // StL h-stride
  __shared__ _Float16 StL[32 * STP];
  const int t = threadIdx.x;
  const int d0 = blockIdx.x * 32;
  const int hcb = blockIdx.y;
  const int b = blockIdx.z;
  const int w = t >> 6, lane = t & 63;
  const int lm = lane & 15, qd = lane >> 4;

  const float av0 = abuf[b * H_ + d0 + lm];
  const float av1 = abuf[b * H_ + d0 + 16 + lm];

  f32x4 acc[MT][2];
#pragma unroll
  for (int mt = 0; mt < MT; ++mt) {
    acc[mt][0] = (f32x4){0.f, 0.f, 0.f, 0.f};
    acc[mt][1] = (f32x4){0.f, 0.f, 0.f, 0.f};
  }

  const size_t ktbase = (size_t)b * H_;
  const size_t krow = (ktbase + hcb * HCH + w * MT * 16 + lm) * S_ + qd * 8;
  const size_t vrow0 = (ktbase + d0 + lm) * S_ + qd * 8;
  const size_t vrow1 = (ktbase + d0 + 16 + lm) * S_ + qd * 8;

  f16x8 kfb[2][MT][2];
  f16x8 vfb[2][2][2];
  // preload block 0
#pragma unroll
  for (int mt = 0; mt < MT; ++mt) {
    kfb[0][mt][0] = *(const f16x8*)&KT[krow + (size_t)mt * 16 * S_];
    kfb[0][mt][1] = *(const f16x8*)&KT[krow + (size_t)mt * 16 * S_ + 32];
  }
  vfb[0][0][0] = *(const f16x8*)&VT[vrow0];
  vfb[0][0][1] = *(const f16x8*)&VT[vrow0 + 32];
  vfb[0][1][0] = *(const f16x8*)&VT[vrow1];
  vfb[0][1][1] = *(const f16x8*)&VT[vrow1 + 32];

  _Float16* Pp = P + (size_t)hcb * pstride;

#pragma unroll 1
  for (int blk = 0; blk < NB_; ++blk) {
    const int cur = blk & 1, nxt = cur ^ 1;
    const int s0 = blk * 64;
    // issue Q loads for this step's output phase
    f16x8 qf[KT2];
    const size_t qrow = ((size_t)b * S_ + s0 + w * 16 + lm) * H_ + hcb * HCH + qd * 8;
#pragma unroll
    for (int kt = 0; kt < KT2; ++kt) qf[kt] = *(const f16x8*)&Qb[qrow + kt * 32];
    // ---- update: St = St*a + K^T V ----
#pragma unroll
    for (int mt = 0; mt < MT; ++mt) {
      f32x4 c0 = acc[mt][0] * av0;
      f32x4 c1 = acc[mt][1] * av1;
      c0 = __builtin_amdgcn_mfma_f32_16x16x32_f16(kfb[cur][mt][0], vfb[cur][0][0], c0, 0, 0, 0);
      c0 = __builtin_amdgcn_mfma_f32_16x16x32_f16(kfb[cur][mt][1], vfb[cur][0][1], c0, 0, 0, 0);
      c1 = __builtin_amdgcn_mfma_f32_16x16x32_f16(kfb[cur][mt][0], vfb[cur][1][0], c1, 0, 0, 0);
      c1 = __builtin_amdgcn_mfma_f32_16x16x32_f16(kfb[cur][mt][1], vfb[cur][1][1], c1, 0, 0, 0);
      acc[mt][0] = c0;
      acc[mt][1] = c1;
    }
    __syncthreads();   // protect previous step's StL readers
    // ---- St -> LDS f16, StL[d][h] ----
#pragma unroll
    for (int mt = 0; mt < MT; ++mt) {
      const int hl = (w * MT + mt) * 16 + qd * 4;
      f16x4 p0, p1;
#pragma unroll
      for (int r = 0; r < 4; ++r) {
        p0[r] = (_Float16)acc[mt][0][r];
        p1[r] = (_Float16)acc[mt][1][r];
      }
      *(f16x4*)&StL[lm * STP + hl] = p0;
      *(f16x4*)&StL[(16 + lm) * STP + hl] = p1;
    }
    __syncthreads();
    // ---- prefetch next block's K/V (lands during output phase) ----
    if (blk < NB_ - 1) {
      const int s1 = s0 + 64;
#pragma unroll
      for (int mt = 0; mt < MT; ++mt) {
        kfb[nxt][mt][0] = *(const f16x8*)&KT[krow + (size_t)mt * 16 * S_ + s1];
        kfb[nxt][mt][1] = *(const f16x8*)&KT[krow + (size_t)mt * 16 * S_ + s1 + 32];
      }
      vfb[nxt][0][0] = *(const f16x8*)&VT[vrow0 + s1];
      vfb[nxt][0][1] = *(const f16x8*)&VT[vrow0 + s1 + 32];
      vfb[nxt][1][0] = *(const f16x8*)&VT[vrow1 + s1];
      vfb[nxt][1][1] = *(const f16x8*)&VT[vrow1 + s1 + 32];
    }
    // ---- output partial^T[d][s] = St^T . Q ----
    f32x4 o0 = (f32x4){0.f, 0.f, 0.f, 0.f};
    f32x4 o1 = (f32x4){0.f, 0.f, 0.f, 0.f};
#pragma unroll
    for (int kt = 0; kt < KT2; ++kt) {
      f16x8 a0 = *(f16x8*)&StL[lm * STP + kt * 32 + qd * 8];
      f16x8 a1 = *(f16x8*)&StL[(16 + lm) * STP + kt * 32 + qd * 8];
      o0 = __builtin_amdgcn_mfma_f32_16x16x32_f16(a0, qf[kt], o0, 0, 0, 0);
      o1 = __builtin_amdgcn_mfma_f32_16x16x32_f16(a1, qf[kt], o1, 0, 0, 0);
    }
    // store P[s][d] (f16x4 along d; rows fill 64B lines across qd quads)
    const size_t prow = ((size_t)b * S_ + s0 + w * 16 + lm) * H_ + d0 + qd * 4;
    f16x4 q0, q1;
#pragma unroll
    for (int r = 0; r < 4; ++r) { q0[r] = (_Float16)o0[r]; q1[r] = (_Float16)o1[r]; }
    *(f16x4*)&Pp[prow] = q0;
    *(f16x4*)&Pp[prow + 16] = q1;
  }
}

// ---------------------------------------------------------------------------
// O += sum_hc P_hc  (elementwise, f16 partials -> f32)
// ---------------------------------------------------------------------------
template<int HC>
__global__ __launch_bounds__(256) void k_reduce(const _Float16* __restrict__ P,
                                                size_t pstride, float* __restrict__ O) {
  const int total = M_ * H_ / 8;
  for (int i = blockIdx.x * 256 + threadIdx.x; i < total; i += gridDim.x * 256) {
    f32x4 o0 = ((f32x4*)O)[i * 2];
    f32x4 o1 = ((f32x4*)O)[i * 2 + 1];
#pragma unroll
    for (int hc = 0; hc < HC; ++hc) {
      f16x8 p = ((const f16x8*)(P + hc * pstride))[i];
#pragma unroll
      for (int j = 0; j < 4; ++j) { o0[j] += (float)p[j]; o1[j] += (float)p[4 + j]; }
    }
    ((f32x4*)O)[i * 2] = o0;
    ((f32x4*)O)[i * 2 + 1] = o1;
  }
}

// ---------------------------------------------------------------------------
extern "C" void kernel_launch(void* const* d_in, const int* in_sizes, int n_in,
                              void* d_out, int out_size, void* d_ws, size_t ws_size,
                              hipStream_t stream) {
  (void)in_sizes; (void)n_in; (void)out_size;
  const float* x    = (const float*)d_in[0];
  const float* Wq   = (const float*)d_in[1];
  const float* Wk   = (const float*)d_in[2];
  const float* Wv   = (const float*)d_in[3];
  const float* W1   = (const float*)d_in[4];
  const float* W2   = (const float*)d_in[5];
  const float* bias = (const float*)d_in[6];
  float* O = (float*)d_out;

  const size_t nQKV = (size_t)M_ * H_;            // elements per f16 buffer
  char* ws = (char*)d_ws;
  _Float16* Qb  = (_Float16*)ws;
  _Float16* KT  = Qb + nQKV;
  _Float16* VT  = KT + nQKV;
  _Float16* WqT = VT + nQKV;
  _Float16* WkT = WqT + H_ * H_;
  _Float16* WvT = WkT + H_ * H_;
  float* tbuf = (float*)(WvT + H_ * H_);
  float* abuf = tbuf + (size_t)M_ * 16;
  _Float16* P = (_Float16*)(abuf + B_ * H_);

  const size_t base = (size_t)((char*)P - ws);
  const bool hc4 = ws_size >= base + 4 * nQKV * sizeof(_Float16);

  k_transpose<<<dim3(24, 24), 256, 0, stream>>>(Wq, WqT);
  k_transpose<<<dim3(24, 24), 256, 0, stream>>>(Wk, WkT);
  k_transpose<<<dim3(24, 24), 256, 0, stream>>>(Wv, WvT);
  k_gemm_qkv<<<dim3(512, 6), 256, 0, stream>>>(x, WqT, WkT, WvT, Qb, KT, VT);
  k_tgemm<<<dim3(512), 256, 0, stream>>>(x, W1, tbuf);
  k_areduce<<<dim3(24, 8), 256, 0, stream>>>(tbuf, W2, bias, abuf);
  k_scores_y<<<dim3(64, 8), 256, 0, stream>>>(Qb, KT, VT, O);
  if (hc4) {
    k_scan<4><<<dim3(24, 4, 8), 256, 0, stream>>>(Qb, KT, VT, abuf, P, nQKV);
    k_reduce<4><<<dim3(4096), 256, 0, stream>>>(P, nQKV, O);
  } else {
    k_scan<2><<<dim3(24, 2, 8), 256, 0, stream>>>(Qb, KT, VT, abuf, P, nQKV);
    k_reduce<2><<<dim3(4096), 256, 0, stream>>>(P, nQKV, O);
  }
}